// Round 1
// baseline (253.114 us; speedup 1.0000x reference)
//
#include <hip/hip_runtime.h>

typedef __attribute__((ext_vector_type(4))) float f32x4;
typedef __attribute__((ext_vector_type(8))) short s16x8;

#define MFMA_16x16x32_BF16 __builtin_amdgcn_mfma_f32_16x16x32_bf16

__device__ __forceinline__ unsigned short f2bf(float f) {
  unsigned int u = __builtin_bit_cast(unsigned int, f);
  unsigned int r = (u + 0x7FFFu + ((u >> 16) & 1u)) >> 16;  // RNE
  return (unsigned short)r;
}

__device__ __forceinline__ float sigm(float x) { return 1.0f / (1.0f + __expf(-x)); }
__device__ __forceinline__ float ftanh(float x) {
  float xx = fminf(fmaxf(x, -15.0f), 15.0f);
  float e = __expf(2.0f * xx);
  return (e - 1.0f) / (e + 1.0f);
}

// ---------------- kernel 0: pack W_ih -> bf16, fused bias ----------------
__global__ __launch_bounds__(256) void pack_kernel(
    const float* __restrict__ Wih, const float* __restrict__ bih,
    const float* __restrict__ bhh, unsigned short* __restrict__ Wihb,
    float* __restrict__ biasC) {
  int i = blockIdx.x * 256 + threadIdx.x;  // 16384 float4 chunks (512*128 elems)
  const float4 v = *reinterpret_cast<const float4*>(Wih + (size_t)i * 4);
  ushort4 u;
  u.x = f2bf(v.x); u.y = f2bf(v.y); u.z = f2bf(v.z); u.w = f2bf(v.w);
  *reinterpret_cast<ushort4*>(Wihb + (size_t)i * 4) = u;
  if (i < 512) biasC[i] = bih[i] + bhh[i];
}

// ---------------- kernel A: attn[b,:] = softmax_d( sum_t x[b,t,:] * wt[t] ) ----
__global__ __launch_bounds__(64) void attn_kernel(
    const float* __restrict__ x, const float* __restrict__ Wattn,
    float* __restrict__ attn) {
  const int b = blockIdx.x;
  const int l = threadIdx.x;  // 0..63
  const float* xb = x + (size_t)b * 64 * 128;
  const float wtl = Wattn[256 + l];  // this lane's wt entry
  float s0 = 0.f, s1 = 0.f;
  for (int t = 0; t < 64; ++t) {
    float w = __shfl(wtl, t, 64);
    s0 = fmaf(xb[t * 128 + l], w, s0);
    s1 = fmaf(xb[t * 128 + 64 + l], w, s1);
  }
  float m = fmaxf(s0, s1);
  for (int off = 32; off; off >>= 1) m = fmaxf(m, __shfl_xor(m, off, 64));
  float e0 = __expf(s0 - m), e1 = __expf(s1 - m);
  float sum = e0 + e1;
  for (int off = 32; off; off >>= 1) sum += __shfl_xor(sum, off, 64);
  float inv = 1.0f / sum;
  attn[(size_t)b * 128 + l] = e0 * inv;
  attn[(size_t)b * 128 + 64 + l] = e1 * inv;
}

// ---------------- kernel B: persistent LSTM recurrence, 16 rows/block ----------
// gates(16x512) = [w_in | h](16x256) @ Wc^T per step, bf16 MFMA 16x16x32.
// Wave w owns interleaved d-slice [32w,32w+32): gate cols {g*128 + w*32 + jj*16}
// so i,f,g,o for a given (row,d) live in the SAME lane -> no gate exchange.
__global__ __launch_bounds__(256, 1) void lstm_kernel(
    const float* __restrict__ x, const float* __restrict__ Whh_f,
    const unsigned short* __restrict__ Wihb, const float* __restrict__ biasC,
    const float* __restrict__ attn, float* __restrict__ out) {
  // Whh staged bf16, row stride 136 (272 B, 16B-aligned, ~2-way banks)
  __shared__ __attribute__((aligned(16))) unsigned short sWhh[512 * 136];
  // A = [w_in | h] 16 x 256 bf16, row stride 264 (528 B)
  __shared__ __attribute__((aligned(16))) unsigned short sA[16 * 264];

  const int tid = threadIdx.x;
  const int l = tid & 63;
  const int w = tid >> 6;     // wave 0..3
  const int l15 = l & 15;
  const int khi = l >> 4;     // 0..3
  const int rowBase = blockIdx.x * 16;

  // ---- stage W_hh (fp32 global -> bf16 LDS) ----
  for (int i = tid; i < 16384; i += 256) {  // 16384 float4 chunks
    const int n = i >> 5;            // row (i*4)/128
    const int k = (i & 31) << 2;     // col (i*4)%128
    const float4 v = *reinterpret_cast<const float4*>(Whh_f + n * 128 + k);
    ushort4 u;
    u.x = f2bf(v.x); u.y = f2bf(v.y); u.z = f2bf(v.z); u.w = f2bf(v.w);
    *reinterpret_cast<ushort4*>(&sWhh[n * 136 + k]) = u;
  }

  // ---- staging role (w_in): thread -> (row r_st, 8 cols at dc_st) ----
  const int r_st = tid >> 4;
  const int dc_st = (tid & 15) << 3;

  // zero h-half of sA (t=0 has h=0)
  {
    int4 z = {0, 0, 0, 0};
    *reinterpret_cast<int4*>(&sA[r_st * 264 + 128 + dc_st]) = z;
  }

  // preload attn for staging role
  float at[8];
#pragma unroll
  for (int j = 0; j < 8; ++j)
    at[j] = attn[(size_t)(rowBase + r_st) * 128 + dc_st + j];

  // preload bias for elementwise role (acc n -> gate g=n>>1, sub-tile jj=n&1)
  float bias[8];
#pragma unroll
  for (int n = 0; n < 8; ++n)
    bias[n] = biasC[(n >> 1) * 128 + w * 32 + (n & 1) * 16 + l15];

  // precompute B-fragment offsets per acc n
  const unsigned short* wihP[8];
  int whhOff[8];
#pragma unroll
  for (int n = 0; n < 8; ++n) {
    const int ncol = (n >> 1) * 128 + w * 32 + (n & 1) * 16 + l15;
    wihP[n] = Wihb + ncol * 128 + khi * 8;
    whhOff[n] = ncol * 136 + khi * 8;
  }

  float c[8], hreg[8];
#pragma unroll
  for (int i = 0; i < 8; ++i) c[i] = 0.0f;

  const float* xrow = x + ((size_t)(rowBase + r_st) * 64) * 128 + dc_st;
  float* outP = out + ((size_t)(rowBase + khi * 4) * 64) * 128 + w * 32 + l15;

  __syncthreads();

  for (int t = 0; t < 64; ++t) {
    // ---- P1: stage w_in = attn * x_t (bf16) into sA[:, 0:128] ----
    {
      const float4 v0 = *reinterpret_cast<const float4*>(xrow + t * 128);
      const float4 v1 = *reinterpret_cast<const float4*>(xrow + t * 128 + 4);
      ushort4 u0, u1;
      u0.x = f2bf(v0.x * at[0]); u0.y = f2bf(v0.y * at[1]);
      u0.z = f2bf(v0.z * at[2]); u0.w = f2bf(v0.w * at[3]);
      u1.x = f2bf(v1.x * at[4]); u1.y = f2bf(v1.y * at[5]);
      u1.z = f2bf(v1.z * at[6]); u1.w = f2bf(v1.w * at[7]);
      unsigned short* dst = &sA[r_st * 264 + dc_st];
      *reinterpret_cast<ushort4*>(dst) = u0;
      *reinterpret_cast<ushort4*>(dst + 4) = u1;
    }
    __syncthreads();  // barrier1: A complete before MFMA reads

    // ---- P2: gates = A @ Wc^T ----
    f32x4 acc[8];
#pragma unroll
    for (int n = 0; n < 8; ++n) acc[n] = f32x4{0.f, 0.f, 0.f, 0.f};
#pragma unroll
    for (int kt = 0; kt < 8; ++kt) {
      const s16x8 af =
          *reinterpret_cast<const s16x8*>(&sA[l15 * 264 + kt * 32 + khi * 8]);
#pragma unroll
      for (int n = 0; n < 8; ++n) {
        s16x8 bfr;
        if (kt < 4)
          bfr = *reinterpret_cast<const s16x8*>(wihP[n] + kt * 32);
        else
          bfr = *reinterpret_cast<const s16x8*>(&sWhh[whhOff[n] + (kt - 4) * 32]);
        acc[n] = MFMA_16x16x32_BF16(af, bfr, acc[n], 0, 0, 0);
      }
    }

    // ---- P3a: elementwise LSTM update + output write (fp32) ----
#pragma unroll
    for (int jj = 0; jj < 2; ++jj) {
#pragma unroll
      for (int rr = 0; rr < 4; ++rr) {
        const float gi = acc[0 + jj][rr] + bias[0 + jj];
        const float gf = acc[2 + jj][rr] + bias[2 + jj];
        const float gg = acc[4 + jj][rr] + bias[4 + jj];
        const float go = acc[6 + jj][rr] + bias[6 + jj];
        const int ci = jj * 4 + rr;
        const float cn = sigm(gf) * c[ci] + sigm(gi) * ftanh(gg);
        c[ci] = cn;
        const float h = sigm(go) * ftanh(cn);
        hreg[ci] = h;
        outP[((size_t)rr * 64 + t) * 128 + jj * 16] = h;
      }
    }
    __syncthreads();  // barrier2: all MFMA reads of sA done before h overwrite

    // ---- P3b: write h (bf16) into sA[:, 128:256] for next step ----
#pragma unroll
    for (int jj = 0; jj < 2; ++jj) {
#pragma unroll
      for (int rr = 0; rr < 4; ++rr) {
        const int row = khi * 4 + rr;
        const int d = w * 32 + jj * 16 + l15;
        sA[row * 264 + 128 + d] = f2bf(hreg[jj * 4 + rr]);
      }
    }
    // no barrier needed: next P1 writes disjoint region; barrier1 orders reads
  }
}

extern "C" void kernel_launch(void* const* d_in, const int* in_sizes, int n_in,
                              void* d_out, int out_size, void* d_ws, size_t ws_size,
                              hipStream_t stream) {
  const float* x     = (const float*)d_in[0];  // (4096, 64, 128)
  const float* W_ih  = (const float*)d_in[1];  // (512, 128)
  const float* W_hh  = (const float*)d_in[2];  // (512, 128)
  const float* b_ih  = (const float*)d_in[3];  // (512,)
  const float* b_hh  = (const float*)d_in[4];  // (512,)
  const float* Wattn = (const float*)d_in[5];  // (1, 320)
  float* out = (float*)d_out;                  // (4096, 64, 128)

  // workspace layout
  float* attn = (float*)d_ws;                                   // 2 MB
  unsigned short* Wihb = (unsigned short*)((char*)d_ws + 4096 * 128 * 4);  // 128 KB
  float* biasC = (float*)((char*)d_ws + 4096 * 128 * 4 + 512 * 128 * 2);  // 2 KB

  pack_kernel<<<64, 256, 0, stream>>>(W_ih, b_ih, b_hh, Wihb, biasC);
  attn_kernel<<<4096, 64, 0, stream>>>(x, Wattn, attn);
  lstm_kernel<<<256, 256, 0, stream>>>(x, W_hh, Wihb, biasC, attn, out);
}

// Round 2
// 117.740 us; speedup vs baseline: 2.1498x; 2.1498x over previous
//
#include <hip/hip_runtime.h>

typedef __attribute__((ext_vector_type(4))) float f32x4;
typedef __attribute__((ext_vector_type(8))) short s16x8;

#define MFMA_16x16x32_BF16 __builtin_amdgcn_mfma_f32_16x16x32_bf16

__device__ __forceinline__ unsigned short f2bf(float f) {
  unsigned int u = __builtin_bit_cast(unsigned int, f);
  unsigned int r = (u + 0x7FFFu + ((u >> 16) & 1u)) >> 16;  // RNE
  return (unsigned short)r;
}

__device__ __forceinline__ float sigm(float x) {
  return __builtin_amdgcn_rcpf(1.0f + __expf(-x));
}
__device__ __forceinline__ float ftanh(float x) {
  float xx = fminf(fmaxf(x, -15.0f), 15.0f);
  float e = __expf(2.0f * xx);
  return 1.0f - 2.0f * __builtin_amdgcn_rcpf(e + 1.0f);
}

// ---- kernel 0: pack Wc = [W_ih | W_hh] (512 x 256) -> bf16, fused bias ----
__global__ __launch_bounds__(256) void pack_kernel(
    const float* __restrict__ Wih, const float* __restrict__ Whh,
    const float* __restrict__ bih, const float* __restrict__ bhh,
    unsigned short* __restrict__ Wc, float* __restrict__ biasC) {
  int i = blockIdx.x * 256 + threadIdx.x;  // 32768 chunks of 4 elems
  int col = i >> 6;
  int k4 = (i & 63) << 2;
  const float* src = (k4 < 128) ? (Wih + col * 128 + k4)
                                : (Whh + col * 128 + (k4 - 128));
  const float4 v = *reinterpret_cast<const float4*>(src);
  ushort4 u;
  u.x = f2bf(v.x); u.y = f2bf(v.y); u.z = f2bf(v.z); u.w = f2bf(v.w);
  *reinterpret_cast<ushort4*>(Wc + (size_t)col * 256 + k4) = u;
  if (i < 512) biasC[i] = bih[i] + bhh[i];
}

// ---- kernel A: attn[b,:] = softmax_d( sum_t x[b,t,:] * wt[t] ) ----
__global__ __launch_bounds__(64) void attn_kernel(
    const float* __restrict__ x, const float* __restrict__ Wattn,
    float* __restrict__ attn) {
  const int b = blockIdx.x;
  const int l = threadIdx.x;  // 0..63
  const float* xb = x + (size_t)b * 64 * 128;
  const float wtl = Wattn[256 + l];
  float s0 = 0.f, s1 = 0.f;
  for (int t = 0; t < 64; ++t) {
    float w = __shfl(wtl, t, 64);
    s0 = fmaf(xb[t * 128 + l], w, s0);
    s1 = fmaf(xb[t * 128 + 64 + l], w, s1);
  }
  float m = fmaxf(s0, s1);
  for (int off = 32; off; off >>= 1) m = fmaxf(m, __shfl_xor(m, off, 64));
  float e0 = __expf(s0 - m), e1 = __expf(s1 - m);
  float sum = e0 + e1;
  for (int off = 32; off; off >>= 1) sum += __shfl_xor(sum, off, 64);
  float inv = 1.0f / sum;
  attn[(size_t)b * 128 + l] = e0 * inv;
  attn[(size_t)b * 128 + 64 + l] = e1 * inv;
}

// ---- kernel B: persistent LSTM recurrence, weights in registers ----
// 512 threads = 8 waves; block handles 16 batch rows. Wave w owns gate cols
// {g*128 + w*16 + l15 : g=0..3} -> 4 acc tiles; i/f/g/o lane-local.
// B-frags (4g x 8kt x 16B = 128 VGPR) loaded ONCE. LDS = one 16x256 bf16
// A-tile [w_in | h], XOR-swizzled (byte ^= (row&7)<<4) for conflict-free
// ds_read_b128.
__global__ __launch_bounds__(512, 2) void lstm_kernel(
    const float* __restrict__ x, const unsigned short* __restrict__ Wc,
    const float* __restrict__ biasC, const float* __restrict__ attn,
    float* __restrict__ out) {
  __shared__ __attribute__((aligned(16))) unsigned short sA[16 * 256];
  char* sAb = reinterpret_cast<char*>(sA);

  const int tid = threadIdx.x;
  const int l = tid & 63;
  const int w = tid >> 6;   // 0..7
  const int l15 = l & 15;
  const int khi = l >> 4;   // 0..3
  const int rowBase = blockIdx.x * 16;

  // ---- load B fragments into registers (once) ----
  s16x8 bfr[4][8];
#pragma unroll
  for (int g = 0; g < 4; ++g) {
    const unsigned short* p =
        Wc + (size_t)(g * 128 + w * 16 + l15) * 256 + khi * 8;
#pragma unroll
    for (int kt = 0; kt < 8; ++kt)
      bfr[g][kt] = *reinterpret_cast<const s16x8*>(p + kt * 32);
  }

  float bias[4];
#pragma unroll
  for (int g = 0; g < 4; ++g) bias[g] = biasC[g * 128 + w * 16 + l15];

  // ---- staging role: thread -> (row r_st, 4 cols at c_st) ----
  const int r_st = tid >> 5;          // 0..15
  const int c_st = (tid & 31) << 2;   // 0..124
  const float4 at =
      *reinterpret_cast<const float4*>(attn + (size_t)(rowBase + r_st) * 128 + c_st);
  const float* xrow = x + (size_t)(rowBase + r_st) * 8192 + c_st;
  char* stg_ptr = sAb + r_st * 512 + ((c_st << 1) ^ ((r_st & 7) << 4));

  // zero h-half (t=0): thread covers row r_st, 8 bytes
  {
    int hb = (256 + ((tid & 31) << 3)) ^ ((r_st & 7) << 4);
    uint2 z = {0u, 0u};
    *reinterpret_cast<uint2*>(sAb + r_st * 512 + hb) = z;
  }

  float c[4] = {0.f, 0.f, 0.f, 0.f};
  float4 xv = *reinterpret_cast<const float4*>(xrow);  // t = 0

  const char* aRd = sAb + l15 * 512;
  float* outP = out + (size_t)(rowBase + khi * 4) * 8192 + w * 16 + l15;

  __syncthreads();

  for (int t = 0; t < 64; ++t) {
    // P1: stage w_in = attn * x_t (bf16)
    {
      ushort4 u;
      u.x = f2bf(xv.x * at.x); u.y = f2bf(xv.y * at.y);
      u.z = f2bf(xv.z * at.z); u.w = f2bf(xv.w * at.w);
      *reinterpret_cast<ushort4*>(stg_ptr) = u;
    }
    // prefetch next x tile (long-latency, consumed next iter)
    const int tn = (t + 1) & 63;
    xv = *reinterpret_cast<const float4*>(xrow + tn * 128);
    __syncthreads();  // A-tile complete

    // P2: gates = A @ Wc^T (K = 256)
    f32x4 acc[4];
#pragma unroll
    for (int g = 0; g < 4; ++g) acc[g] = f32x4{0.f, 0.f, 0.f, 0.f};
#pragma unroll
    for (int kt = 0; kt < 8; ++kt) {
      const int off = (kt * 64 + khi * 16) ^ ((l15 & 7) << 4);
      const s16x8 af = *reinterpret_cast<const s16x8*>(aRd + off);
#pragma unroll
      for (int g = 0; g < 4; ++g)
        acc[g] = MFMA_16x16x32_BF16(af, bfr[g][kt], acc[g], 0, 0, 0);
    }

    // P3a: elementwise LSTM cell + output store (fp32)
    float hreg[4];
#pragma unroll
    for (int rr = 0; rr < 4; ++rr) {
      const float gi = acc[0][rr] + bias[0];
      const float gf = acc[1][rr] + bias[1];
      const float gg = acc[2][rr] + bias[2];
      const float go = acc[3][rr] + bias[3];
      const float cn = sigm(gf) * c[rr] + sigm(gi) * ftanh(gg);
      c[rr] = cn;
      const float h = sigm(go) * ftanh(cn);
      hreg[rr] = h;
      outP[(size_t)rr * 8192 + t * 128] = h;
    }
    __syncthreads();  // all MFMA reads of sA done

    // P3b: write h (bf16) into h-half for next step
#pragma unroll
    for (int rr = 0; rr < 4; ++rr) {
      const int row = khi * 4 + rr;
      const int hb = (256 + ((w * 16 + l15) << 1)) ^ ((row & 7) << 4);
      *reinterpret_cast<unsigned short*>(sAb + row * 512 + hb) = f2bf(hreg[rr]);
    }
  }
}

extern "C" void kernel_launch(void* const* d_in, const int* in_sizes, int n_in,
                              void* d_out, int out_size, void* d_ws, size_t ws_size,
                              hipStream_t stream) {
  const float* x     = (const float*)d_in[0];  // (4096, 64, 128)
  const float* W_ih  = (const float*)d_in[1];  // (512, 128)
  const float* W_hh  = (const float*)d_in[2];  // (512, 128)
  const float* b_ih  = (const float*)d_in[3];  // (512,)
  const float* b_hh  = (const float*)d_in[4];  // (512,)
  const float* Wattn = (const float*)d_in[5];  // (1, 320)
  float* out = (float*)d_out;                  // (4096, 64, 128)

  // workspace layout
  float* attn = (float*)d_ws;                                         // 2 MB
  unsigned short* Wc = (unsigned short*)((char*)d_ws + 4096 * 128 * 4);  // 256 KB
  float* biasC = (float*)((char*)d_ws + 4096 * 128 * 4 + 512 * 256 * 2); // 2 KB

  pack_kernel<<<128, 256, 0, stream>>>(W_ih, W_hh, b_ih, b_hh, Wc, biasC);
  attn_kernel<<<4096, 64, 0, stream>>>(x, Wattn, attn);
  lstm_kernel<<<256, 512, 0, stream>>>(x, Wc, biasC, attn, out);
}